// Round 9
// baseline (87.684 us; speedup 1.0000x reference)
//
#include <hip/hip_runtime.h>
#include <stdint.h>

// Problem constants (match reference)
#define BB 4
#define NN 16384
#define SS 4096
#define CC 64
#define KK 32
#define R2F 0.04f
#define EPSF 1e-5f   // f32 screen band; f32 d2 abs err bound ~5e-7, 20x margin

#define TILE_S 256   // s-span per group block

typedef float vfloat4 __attribute__((ext_vector_type(4)));  // NT-store-compatible

// ws layout:
//   [0, 1MB)    packed float4 {x,y,z,|p|^2}
//   [1MB, 3MB)  idx int32 [B,S,K]
#define PACKED_BYTES ((size_t)BB * NN * sizeof(float4))

static __device__ __forceinline__ void nt_store4(float* p, float a, float b,
                                                 float c, float d) {
    vfloat4 v = {a, b, c, d};
    __builtin_nontemporal_store(v, (vfloat4*)p);
}

// ---------------------------------------------------------------------------
// Kernel 0: pack xyz -> float4 {x,y,z,|p|^2_f32} (w used ONLY for f32 screen)
// ---------------------------------------------------------------------------
__global__ __launch_bounds__(256) void pack_kernel(const float* __restrict__ xyz,
                                                   float4* __restrict__ packed) {
    for (int i = 0; i < 4; ++i) {
        int p = (int)blockIdx.x * 1024 + i * 256 + (int)threadIdx.x;
        float x = xyz[(size_t)p * 3 + 0];
        float y = xyz[(size_t)p * 3 + 1];
        float z = xyz[(size_t)p * 3 + 2];
        float w = fmaf(z, z, fmaf(y, y, x * x));
        packed[p] = make_float4(x, y, z, w);
    }
}

// ---------------------------------------------------------------------------
// Kernel 1: ball query — one wave per centroid, independent (no barriers),
// 2-deep prefetch. f32 FMA screen; |d2-R2|<EPS lanes recheck in exact f64 ->
// decisions bit-identical to the f64 numpy reference (absmax 0.0 since R2).
// First KK in-index-order; tail slots filled with first found (0 if none).
// ---------------------------------------------------------------------------
__global__ __launch_bounds__(256) void ballq_kernel(const float4* __restrict__ packed,
                                                    const float* __restrict__ new_xyz,
                                                    int* __restrict__ idx) {
    int wid  = (int)((blockIdx.x * blockDim.x + threadIdx.x) >> 6);  // centroid
    int lane = (int)(threadIdx.x & 63);
    int b = wid >> 12;
    int s = wid & (SS - 1);

    const float* nc = new_xyz + (size_t)(b * SS + s) * 3;
    const float nxf = nc[0], nyf = nc[1], nzf = nc[2];
    const float t1f = fmaf(nzf, nzf, fmaf(nyf, nyf, nxf * nxf));
    const double nx = (double)nxf, ny = (double)nyf, nz = (double)nzf;
    const double t1 = nx * nx + ny * ny + nz * nz;
    const double r2 = 0.2 * 0.2;

    const float4* pts = packed + (size_t)b * NN;
    int* out = idx + (size_t)wid * KK;

    int cnt = 0;
    int first = 0;
    float4 c0 = pts[lane];
    float4 c1 = pts[64 + lane];
    for (int base = 0; base < NN; base += 64) {
        int nb = (base + 128 < NN) ? (base + 128) : base;
        float4 c2 = pts[nb + lane];
        float dotf = fmaf(nzf, c0.z, fmaf(nyf, c0.y, nxf * c0.x));
        float d2f  = fmaf(-2.0f, dotf, t1f + c0.w);
        bool inb;
        if (__builtin_fabsf(d2f - R2F) < EPSF) {
            double px = (double)c0.x, py = (double)c0.y, pz = (double)c0.z;
            double t2  = px * px + py * py + pz * pz;
            double dot = nx * px + ny * py + nz * pz;
            inb = ((t1 + t2) - 2.0 * dot) < r2;
        } else {
            inb = d2f < R2F;
        }
        unsigned long long mask = __ballot(inb);
        if (cnt == 0 && mask != 0ull)
            first = base + (int)__builtin_ctzll(mask);
        if (inb) {
            int slot = cnt + (int)__popcll(mask & ((1ull << lane) - 1ull));
            if (slot < KK) out[slot] = base + lane;
        }
        cnt += (int)__popcll(mask);
        if (cnt >= KK) break;
        c0 = c1; c1 = c2;
    }
    if (lane >= cnt && lane < KK) out[lane] = first;   // fill (0 if none)
}

// ---------------------------------------------------------------------------
// Kernel 2: group + concat, channel-major. Block = (b, ch, 256-s tile).
// 8 passes/thread: coalesced int4 idx load -> 4 gathers from the 64KB
// features[b,c,:] row (L1/L2-resident; 64KB working set is immune to the
// output-stream L2 thrash that bound v7) -> NT float4 store (4KB contiguous
// per pass per block). Chunked bijective XCD swizzle (4288 = 8*536): each
// XCD's row set ~2MB < 4MB L2.
// ---------------------------------------------------------------------------
__global__ __launch_bounds__(256) void group_kernel(const float4* __restrict__ packed,
                                                    const float* __restrict__ new_xyz,
                                                    const float* __restrict__ features,
                                                    const int* __restrict__ idx,
                                                    float* __restrict__ out) {
    int bid = (int)blockIdx.x;
    int wg  = (bid & 7) * 536 + (bid >> 3);   // bijective: 4288 % 8 == 0
    int tile = wg & 15;                       // SS / TILE_S = 16
    int bc   = wg >> 4;                       // b*67 + ch
    int b  = bc / 67;
    int ch = bc - b * 67;
    int s0 = tile * TILE_S;
    int t  = (int)threadIdx.x;
    int k0 = (t & 7) << 2;

    const int* ib = idx + (size_t)b * SS * KK;
    size_t obase = (size_t)bc * SS * KK;

    if (ch >= 3) {
        const float* f = features + ((size_t)b * CC + (ch - 3)) * NN;
#pragma unroll
        for (int p = 0; p < TILE_S / 32; ++p) {
            int s = s0 + p * 32 + (t >> 3);
            int4 jj = *(const int4*)(ib + (size_t)s * KK + k0);
            nt_store4(out + obase + (size_t)s * KK + k0,
                      f[jj.x], f[jj.y], f[jj.z], f[jj.w]);
        }
    } else {
        const float4* pts = packed + (size_t)b * NN;
#pragma unroll
        for (int p = 0; p < TILE_S / 32; ++p) {
            int s = s0 + p * 32 + (t >> 3);
            int4 jj = *(const int4*)(ib + (size_t)s * KK + k0);
            float nv = new_xyz[(size_t)(b * SS + s) * 3 + ch];
            float4 p0 = pts[jj.x], p1 = pts[jj.y], p2 = pts[jj.z], p3 = pts[jj.w];
            float a0, a1, a2, a3;
            if (ch == 0)      { a0 = p0.x; a1 = p1.x; a2 = p2.x; a3 = p3.x; }
            else if (ch == 1) { a0 = p0.y; a1 = p1.y; a2 = p2.y; a3 = p3.y; }
            else              { a0 = p0.z; a1 = p1.z; a2 = p2.z; a3 = p3.z; }
            nt_store4(out + obase + (size_t)s * KK + k0,
                      a0 - nv, a1 - nv, a2 - nv, a3 - nv);
        }
    }
}

extern "C" void kernel_launch(void* const* d_in, const int* in_sizes, int n_in,
                              void* d_out, int out_size, void* d_ws, size_t ws_size,
                              hipStream_t stream) {
    const float* xyz      = (const float*)d_in[0];   // [B,N,3]
    const float* new_xyz  = (const float*)d_in[1];   // [B,S,3]
    const float* features = (const float*)d_in[2];   // [B,C,N]
    float* out = (float*)d_out;                      // [B,67,S,K]

    float4* packed = (float4*)d_ws;
    int*    idx    = (int*)((char*)d_ws + PACKED_BYTES);

    pack_kernel<<<BB * NN / 1024, 256, 0, stream>>>(xyz, packed);
    ballq_kernel<<<(BB * SS) / 4, 256, 0, stream>>>(packed, new_xyz, idx);
    group_kernel<<<BB * 67 * (SS / TILE_S), 256, 0, stream>>>(packed, new_xyz,
                                                              features, idx, out);
}

// Round 10
// 77.222 us; speedup vs baseline: 1.1355x; 1.1355x over previous
//
#include <hip/hip_runtime.h>
#include <stdint.h>

// Problem constants (match reference)
#define BB 4
#define NN 16384
#define SS 4096
#define CC 64
#define KK 32
#define R2F 0.04f
#define EPSF 1e-5f   // f32 screen band; f32 d2 abs err bound ~5e-7, 20x margin

typedef float vfloat4 __attribute__((ext_vector_type(4)));

// ws layout:
//   [0, 1MB)    packed float4 {x,y,z,|p|^2}
//   [1MB, 3MB)  idx int32 [B,S,K]
//   [3MB, 19MB) featH float [B][2][N][32]  (channel-halved transpose)
#define PACKED_BYTES ((size_t)BB * NN * sizeof(float4))
#define IDX_BYTES    ((size_t)BB * SS * KK * sizeof(int))
#define FEATH_BYTES  ((size_t)BB * NN * CC * sizeof(float))

static __device__ __forceinline__ void nt_store(float v, float* p) {
    __builtin_nontemporal_store(v, p);
}

// ---------------------------------------------------------------------------
// Kernel 0: prep = pack (blocks 0..63) + halved transpose (blocks 64..1087).
// featH[b][h][n][c'] : c = h*32+c', rows of 128B (one cache line).
// ---------------------------------------------------------------------------
__global__ __launch_bounds__(256) void prep_kernel(const float* __restrict__ xyz,
                                                   const float* __restrict__ features,
                                                   float4* __restrict__ packed,
                                                   float* __restrict__ featH) {
    int blk = blockIdx.x;
    if (blk < 64) {
        for (int i = 0; i < 4; ++i) {
            int p = blk * 1024 + i * 256 + (int)threadIdx.x;
            float x = xyz[(size_t)p * 3 + 0];
            float y = xyz[(size_t)p * 3 + 1];
            float z = xyz[(size_t)p * 3 + 2];
            float w = fmaf(z, z, fmaf(y, y, x * x));
            packed[p] = make_float4(x, y, z, w);
        }
        return;
    }
    blk -= 64;
    int b  = blk >> 8;               // NN/64 = 256 tiles per b
    int n0 = (blk & 255) << 6;
    const float* f = features + (size_t)b * CC * NN;
    for (int i = 0; i < 4; ++i) {
        int e  = (int)threadIdx.x + i * 256;   // 0..1023
        int c4 = e & 15;
        int n  = n0 + (e >> 4);
        float4 v;
        v.x = f[(size_t)(c4 * 4 + 0) * NN + n];
        v.y = f[(size_t)(c4 * 4 + 1) * NN + n];
        v.z = f[(size_t)(c4 * 4 + 2) * NN + n];
        v.w = f[(size_t)(c4 * 4 + 3) * NN + n];
        int h = c4 >> 3;
        *(float4*)(featH + (((size_t)(b * 2 + h) * NN + n) * 32) + (c4 & 7) * 4) = v;
    }
}

// ---------------------------------------------------------------------------
// Kernel 1: ball query — one wave per centroid, independent, 2-deep prefetch.
// f32 FMA screen; |d2-R2|<EPS lanes recheck in exact f64 -> decisions
// bit-identical to the f64 numpy reference (absmax 0.0 since R2).
// ---------------------------------------------------------------------------
__global__ __launch_bounds__(256) void ballq_kernel(const float4* __restrict__ packed,
                                                    const float* __restrict__ new_xyz,
                                                    int* __restrict__ idx) {
    int wid  = (int)((blockIdx.x * blockDim.x + threadIdx.x) >> 6);  // centroid
    int lane = (int)(threadIdx.x & 63);
    int b = wid >> 12;
    int s = wid & (SS - 1);

    const float* nc = new_xyz + (size_t)(b * SS + s) * 3;
    const float nxf = nc[0], nyf = nc[1], nzf = nc[2];
    const float t1f = fmaf(nzf, nzf, fmaf(nyf, nyf, nxf * nxf));
    const double nx = (double)nxf, ny = (double)nyf, nz = (double)nzf;
    const double t1 = nx * nx + ny * ny + nz * nz;
    const double r2 = 0.2 * 0.2;

    const float4* pts = packed + (size_t)b * NN;
    int* out = idx + (size_t)wid * KK;

    int cnt = 0;
    int first = 0;
    float4 c0 = pts[lane];
    float4 c1 = pts[64 + lane];
    for (int base = 0; base < NN; base += 64) {
        int nb = (base + 128 < NN) ? (base + 128) : base;
        float4 c2 = pts[nb + lane];
        float dotf = fmaf(nzf, c0.z, fmaf(nyf, c0.y, nxf * c0.x));
        float d2f  = fmaf(-2.0f, dotf, t1f + c0.w);
        bool inb;
        if (__builtin_fabsf(d2f - R2F) < EPSF) {
            double px = (double)c0.x, py = (double)c0.y, pz = (double)c0.z;
            double t2  = px * px + py * py + pz * pz;
            double dot = nx * px + ny * py + nz * pz;
            inb = ((t1 + t2) - 2.0 * dot) < r2;
        } else {
            inb = d2f < R2F;
        }
        unsigned long long mask = __ballot(inb);
        if (cnt == 0 && mask != 0ull)
            first = base + (int)__builtin_ctzll(mask);
        if (inb) {
            int slot = cnt + (int)__popcll(mask & ((1ull << lane) - 1ull));
            if (slot < KK) out[slot] = base + lane;
        }
        cnt += (int)__popcll(mask);
        if (cnt >= KK) break;
        c0 = c1; c1 = c2;
    }
    if (lane >= cnt && lane < KK) out[lane] = first;   // fill (0 if none)
}

// ---------------------------------------------------------------------------
// Kernel 2: group — block = (b, h, 4 centroids), 2 passes of 2 centroids.
// Stage 64 featH rows (128B dense lines) into LDS (8KB, swizzled so b128
// readback has 8-lane groups covering all 32 banks), then NT-store
// 32 channels x 64 (2s x 32k contiguous). h==0 blocks also write the 3 xyz
// channels from packed gathers. XCD swizzle (8192 = 8*1024, bijective):
// XCD x touches only featH[b=x/2][h=x%2] = 2MB < 4MB L2 -> gathers stay
// L2-resident under the 137MB write stream.
// ---------------------------------------------------------------------------
__global__ __launch_bounds__(256) void group_kernel(const float4* __restrict__ packed,
                                                    const float* __restrict__ new_xyz,
                                                    const float* __restrict__ featH,
                                                    const int* __restrict__ idx,
                                                    float* __restrict__ out) {
    __shared__ int    sidx[128];
    __shared__ float4 sfeat[64][8];    // 8KB; col = (q + row) & 7

    int bid  = (int)blockIdx.x;
    int wgid = (bid & 7) * 1024 + (bid >> 3);   // bijective: 8192 % 8 == 0
    int b  = wgid >> 11;
    int h  = (wgid >> 10) & 1;
    int s0 = (wgid & 1023) << 2;
    int t  = (int)threadIdx.x;
    int w = t >> 6, lane = t & 63;

    if (t < 128)
        sidx[t] = idx[((size_t)(b * SS + s0 + (t >> 5))) * KK + (t & 31)];
    __syncthreads();

    const size_t cs = (size_t)SS * KK;
    const float* fh = featH + (size_t)(b * 2 + h) * NN * 32;

    // xyz channels (h==0 only): 3 x 4 centroids x 32 k
    if (h == 0 && t < 128) {
        int cl = t >> 5, k = t & 31;
        int s  = s0 + cl;
        int j  = sidx[t];
        float4 p = packed[(size_t)b * NN + j];
        const float* nc = new_xyz + (size_t)(b * SS + s) * 3;
        size_t o = (size_t)(b * 67) * cs + (size_t)s * KK + k;
        nt_store(p.x - nc[0], out + o);
        nt_store(p.y - nc[1], out + o + cs);
        nt_store(p.z - nc[2], out + o + 2 * cs);
    }

    for (int pass = 0; pass < 2; ++pass) {
        // stage 64 rows x 8 float4 (128B/row, one line each)
        for (int i = 0; i < 2; ++i) {
            int slot = i * 256 + t;            // 0..511
            int rl = slot >> 3;                // row 0..63
            int q  = slot & 7;
            const float4* src = (const float4*)(fh + (size_t)sidx[pass * 64 + rl] * 32);
            sfeat[rl][(q + rl) & 7] = src[q];
        }
        __syncthreads();
        // write: 8 c4-groups over 4 waves x 2; lane = row (2 centroids x 32k)
        size_t obase = (size_t)(b * 67 + 3 + h * 32) * cs
                     + (size_t)(s0 + pass * 2) * KK + lane;
        for (int cc = 0; cc < 2; ++cc) {
            int c4 = w * 2 + cc;                        // wave-uniform 0..7
            float4 v = sfeat[lane][(c4 + lane) & 7];    // one ds_read_b128
            nt_store(v.x, out + obase + (size_t)(c4 * 4 + 0) * cs);
            nt_store(v.y, out + obase + (size_t)(c4 * 4 + 1) * cs);
            nt_store(v.z, out + obase + (size_t)(c4 * 4 + 2) * cs);
            nt_store(v.w, out + obase + (size_t)(c4 * 4 + 3) * cs);
        }
        __syncthreads();   // before sfeat reuse
    }
}

extern "C" void kernel_launch(void* const* d_in, const int* in_sizes, int n_in,
                              void* d_out, int out_size, void* d_ws, size_t ws_size,
                              hipStream_t stream) {
    const float* xyz      = (const float*)d_in[0];   // [B,N,3]
    const float* new_xyz  = (const float*)d_in[1];   // [B,S,3]
    const float* features = (const float*)d_in[2];   // [B,C,N]
    float* out = (float*)d_out;                      // [B,67,S,K]

    float4* packed = (float4*)d_ws;
    int*    idx    = (int*)((char*)d_ws + PACKED_BYTES);
    float*  featH  = (float*)((char*)d_ws + PACKED_BYTES + IDX_BYTES);

    prep_kernel<<<64 + BB * (NN / 64), 256, 0, stream>>>(xyz, features, packed, featH);
    ballq_kernel<<<(BB * SS) / 4, 256, 0, stream>>>(packed, new_xyz, idx);
    group_kernel<<<BB * 2 * (SS / 4), 256, 0, stream>>>(packed, new_xyz, featH, idx, out);
}

// Round 11
// 75.187 us; speedup vs baseline: 1.1662x; 1.0271x over previous
//
#include <hip/hip_runtime.h>
#include <stdint.h>

// Problem constants (match reference)
#define BB 4
#define NN 16384
#define SS 4096
#define CC 64
#define KK 32
#define R2F 0.04f
#define EPSF 1e-5f   // f32 screen band; f32 d2 abs err bound ~5e-7, 20x margin

// ws layout:
//   [0, 1MB)    packed float4 {x,y,z,|p|^2}
//   [1MB, 3MB)  idx int32 [B,S,K]   (fallback path only)
//   [3MB, 19MB) featT float [B,N,C]
#define PACKED_BYTES ((size_t)BB * NN * sizeof(float4))
#define IDX_BYTES    ((size_t)BB * SS * KK * sizeof(int))
#define FEATT_BYTES  ((size_t)BB * NN * CC * sizeof(float))

static __device__ __forceinline__ void nt_store(float v, float* p) {
    __builtin_nontemporal_store(v, p);
}

// ---------------------------------------------------------------------------
// Kernel 0: prep = pack (blocks 0..63) + transpose (blocks 64..1087).
// featT[b][n][c]: 256B dense rows.
// ---------------------------------------------------------------------------
__global__ __launch_bounds__(256) void prep_kernel(const float* __restrict__ xyz,
                                                   const float* __restrict__ features,
                                                   float4* __restrict__ packed,
                                                   float* __restrict__ featT) {
    int blk = blockIdx.x;
    if (blk < 64) {
        for (int i = 0; i < 4; ++i) {
            int p = blk * 1024 + i * 256 + (int)threadIdx.x;
            float x = xyz[(size_t)p * 3 + 0];
            float y = xyz[(size_t)p * 3 + 1];
            float z = xyz[(size_t)p * 3 + 2];
            float w = fmaf(z, z, fmaf(y, y, x * x));
            packed[p] = make_float4(x, y, z, w);
        }
        return;
    }
    blk -= 64;
    int b  = blk >> 8;               // NN/64 = 256 tiles per b
    int n0 = (blk & 255) << 6;
    const float* f = features + (size_t)b * CC * NN;
    for (int i = 0; i < 4; ++i) {
        int e  = (int)threadIdx.x + i * 256;   // 0..1023
        int c4 = e & 15;
        int n  = n0 + (e >> 4);
        float4 v;
        v.x = f[(size_t)(c4 * 4 + 0) * NN + n];
        v.y = f[(size_t)(c4 * 4 + 1) * NN + n];
        v.z = f[(size_t)(c4 * 4 + 2) * NN + n];
        v.w = f[(size_t)(c4 * 4 + 3) * NN + n];
        *(float4*)(featT + ((size_t)b * NN + n) * CC + c4 * 4) = v;
    }
}

// ---------------------------------------------------------------------------
// Kernel 1 (fused v11): block = 8 waves = 8 consecutive centroids.
// Phase A: per-wave independent scan (R7-proven; f32 screen + f64 borderline
//   -> decisions bit-identical to the f64 numpy ref, absmax 0.0 since R2).
// Phase B: stage all 256 gathered featT rows (256B dense) into 64KB LDS,
//   XOR-swizzled (col ^ (row&15)) -> b128 conflict-free write AND read.
// Phase C: per channel-quad c4 (2 per wave): 4x ds_read_b128 (j-blocks of 64
//   points), then stores ordered CHANNEL-MAJOR: each channel's 4x256B chunks
//   issued back-to-back = 1KB sequential stream per channel (the variable
//   under test vs R7's isolated 256B chunks).
// ---------------------------------------------------------------------------
__global__ __launch_bounds__(512) void fused_kernel(const float4* __restrict__ packed,
                                                    const float* __restrict__ new_xyz,
                                                    const float* __restrict__ featT,
                                                    float* __restrict__ out) {
    __shared__ float4 sfeat[256][16];   // 64KB; phys col = c4 ^ (row & 15)
    __shared__ int    sidx[256];
    __shared__ float  sxyz[3][256];
    __shared__ float  snc[8 * 3];

    int bid  = (int)blockIdx.x;
    int wgid = (bid & 7) * 256 + (bid >> 3);   // bijective: 2048 % 8 == 0
    int b  = wgid >> 9;                        // 512 blocks per b
    int s0 = (wgid & 511) << 3;
    int t  = (int)threadIdx.x;
    int w = t >> 6, lane = t & 63;
    int s = s0 + w;

    const float* nc = new_xyz + (size_t)(b * SS + s) * 3;
    const float nxf = nc[0], nyf = nc[1], nzf = nc[2];
    if (lane < 3) snc[w * 3 + lane] = nc[lane];
    const float t1f = fmaf(nzf, nzf, fmaf(nyf, nyf, nxf * nxf));
    const double nx = (double)nxf, ny = (double)nyf, nz = (double)nzf;
    const double t1 = nx * nx + ny * ny + nz * nz;
    const double r2 = 0.2 * 0.2;

    const float4* pts = packed + (size_t)b * NN;

    // ---- Phase A: per-wave scan, 2-deep prefetch ----
    int cnt = 0;
    int first = 0;
    float4 c0 = pts[lane];
    float4 c1 = pts[64 + lane];
    for (int base = 0; base < NN; base += 64) {
        int nb = (base + 128 < NN) ? (base + 128) : base;
        float4 c2 = pts[nb + lane];
        float dotf = fmaf(nzf, c0.z, fmaf(nyf, c0.y, nxf * c0.x));
        float d2f  = fmaf(-2.0f, dotf, t1f + c0.w);
        bool inb;
        if (__builtin_fabsf(d2f - R2F) < EPSF) {
            double px = (double)c0.x, py = (double)c0.y, pz = (double)c0.z;
            double t2  = px * px + py * py + pz * pz;
            double dot = nx * px + ny * py + nz * pz;
            inb = ((t1 + t2) - 2.0 * dot) < r2;
        } else {
            inb = d2f < R2F;
        }
        unsigned long long mask = __ballot(inb);
        if (cnt == 0 && mask != 0ull)
            first = base + (int)__builtin_ctzll(mask);
        if (inb) {
            int slot = cnt + (int)__popcll(mask & ((1ull << lane) - 1ull));
            if (slot < KK) {
                int r = w * KK + slot;
                sidx[r] = base + lane;
                sxyz[0][r] = c0.x; sxyz[1][r] = c0.y; sxyz[2][r] = c0.z;
            }
        }
        cnt += (int)__popcll(mask);
        if (cnt >= KK) break;
        c0 = c1; c1 = c2;
    }
    if (lane >= cnt && lane < KK) {       // fill tail with first (0 if none)
        float4 p = pts[first];            // broadcast
        int r = w * KK + lane;
        sidx[r] = first;
        sxyz[0][r] = p.x; sxyz[1][r] = p.y; sxyz[2][r] = p.z;
    }
    __syncthreads();

    // ---- Phase B: stage 256 rows x 256B into swizzled LDS ----
    for (int sweep = 0; sweep < 8; ++sweep) {
        int row = sweep * 32 + (t >> 4);       // 32 rows/sweep, 16 lanes/row
        int cq  = t & 15;
        const float4* src = (const float4*)(featT + ((size_t)b * NN + sidx[row]) * CC);
        sfeat[row][cq ^ (row & 15)] = src[cq];
    }
    __syncthreads();

    // ---- Phase C: writes, 1KB sequential per channel ----
    const size_t cs = (size_t)SS * KK;
    size_t obase = (size_t)(b * 67) * cs + (size_t)s0 * KK;

    for (int half = 0; half < 2; ++half) {
        int c4 = w + half * 8;                 // wave-uniform 0..15
        int col = c4 ^ (lane & 15);
        float4 v0 = sfeat[lane      ][col];    // ds_read_b128, conflict-free
        float4 v1 = sfeat[64  + lane][col];
        float4 v2 = sfeat[128 + lane][col];
        float4 v3 = sfeat[192 + lane][col];
        float* pb = out + obase + (size_t)(3 + c4 * 4) * cs + lane;
        nt_store(v0.x, pb);       nt_store(v1.x, pb + 64);
        nt_store(v2.x, pb + 128); nt_store(v3.x, pb + 192);
        pb += cs;
        nt_store(v0.y, pb);       nt_store(v1.y, pb + 64);
        nt_store(v2.y, pb + 128); nt_store(v3.y, pb + 192);
        pb += cs;
        nt_store(v0.z, pb);       nt_store(v1.z, pb + 64);
        nt_store(v2.z, pb + 128); nt_store(v3.z, pb + 192);
        pb += cs;
        nt_store(v0.w, pb);       nt_store(v1.w, pb + 64);
        nt_store(v2.w, pb + 128); nt_store(v3.w, pb + 192);
    }
    // xyz channels: waves 0..2, channel = w, 1KB sequential each
    if (w < 3) {
        float* pb = out + obase + (size_t)w * cs + lane;
        for (int j = 0; j < 4; ++j) {
            int r = j * 64 + lane;
            float val = sxyz[w][r] - snc[(r >> 5) * 3 + w];
            nt_store(val, pb + j * 64);
        }
    }
}

// ---------------------------------------------------------------------------
// Fallback path (ws too small for featT): pack + ballq + channel-major group
// ---------------------------------------------------------------------------
__global__ __launch_bounds__(256) void ballq_kernel(const float4* __restrict__ packed,
                                                    const float* __restrict__ new_xyz,
                                                    int* __restrict__ idx) {
    int wid  = (int)((blockIdx.x * blockDim.x + threadIdx.x) >> 6);
    int lane = (int)(threadIdx.x & 63);
    int b = wid >> 12;
    int s = wid & (SS - 1);

    const float* nc = new_xyz + (size_t)(b * SS + s) * 3;
    const double nx = (double)nc[0], ny = (double)nc[1], nz = (double)nc[2];
    const double t1 = nx * nx + ny * ny + nz * nz;
    const double r2 = 0.2 * 0.2;

    const float4* pts = packed + (size_t)b * NN;
    int* out = idx + (size_t)wid * KK;

    int cnt = 0;
    int first = 0;
    for (int base = 0; base < NN; base += 64) {
        float4 p = pts[base + lane];
        double px = (double)p.x, py = (double)p.y, pz = (double)p.z;
        double t2  = px * px + py * py + pz * pz;
        double dot = nx * px + ny * py + nz * pz;
        bool inb = ((t1 + t2) - 2.0 * dot) < r2;
        unsigned long long mask = __ballot(inb);
        if (cnt == 0 && mask != 0ull)
            first = base + (int)__builtin_ctzll(mask);
        if (inb) {
            unsigned long long lt = mask & ((1ull << lane) - 1ull);
            int slot = cnt + (int)__popcll(lt);
            if (slot < KK) out[slot] = base + lane;
        }
        cnt += (int)__popcll(mask);
        if (cnt >= KK) break;
    }
    if (cnt < KK && lane >= cnt && lane < KK) out[lane] = first;
}

__global__ __launch_bounds__(256) void group_kernel(const float4* __restrict__ packed,
                                                    const float* __restrict__ new_xyz,
                                                    const float* __restrict__ features,
                                                    const int* __restrict__ idx,
                                                    float* __restrict__ out) {
    int bc = blockIdx.x >> 7;
    int s5 = blockIdx.x & 127;
    int b  = bc / 67;
    int ch = bc - b * 67;
    int s  = (s5 << 5) | ((int)threadIdx.x >> 3);
    int k0 = ((int)threadIdx.x & 7) << 2;

    const int4 jj = *(const int4*)(idx + ((size_t)(b * SS + s) * KK + k0));
    size_t oaddr = ((size_t)bc * SS + s) * KK + k0;

    float4 r;
    if (ch < 3) {
        const float4* pts = packed + (size_t)b * NN;
        float4 p0 = pts[jj.x], p1 = pts[jj.y], p2 = pts[jj.z], p3 = pts[jj.w];
        float nc = new_xyz[(size_t)(b * SS + s) * 3 + ch];
        float a0, a1, a2, a3;
        if (ch == 0)      { a0 = p0.x; a1 = p1.x; a2 = p2.x; a3 = p3.x; }
        else if (ch == 1) { a0 = p0.y; a1 = p1.y; a2 = p2.y; a3 = p3.y; }
        else              { a0 = p0.z; a1 = p1.z; a2 = p2.z; a3 = p3.z; }
        r = make_float4(a0 - nc, a1 - nc, a2 - nc, a3 - nc);
    } else {
        const float* f = features + ((size_t)b * CC + (ch - 3)) * NN;
        r = make_float4(f[jj.x], f[jj.y], f[jj.z], f[jj.w]);
    }
    *(float4*)(out + oaddr) = r;
}

extern "C" void kernel_launch(void* const* d_in, const int* in_sizes, int n_in,
                              void* d_out, int out_size, void* d_ws, size_t ws_size,
                              hipStream_t stream) {
    const float* xyz      = (const float*)d_in[0];   // [B,N,3]
    const float* new_xyz  = (const float*)d_in[1];   // [B,S,3]
    const float* features = (const float*)d_in[2];   // [B,C,N]
    float* out = (float*)d_out;                      // [B,67,S,K]

    float4* packed = (float4*)d_ws;
    int*    idx    = (int*)((char*)d_ws + PACKED_BYTES);
    float*  featT  = (float*)((char*)d_ws + PACKED_BYTES + IDX_BYTES);

    bool fast = ws_size >= PACKED_BYTES + IDX_BYTES + FEATT_BYTES;

    if (fast) {
        prep_kernel<<<64 + BB * (NN / 64), 256, 0, stream>>>(xyz, features, packed, featT);
        fused_kernel<<<BB * SS / 8, 512, 0, stream>>>(packed, new_xyz, featT, out);
    } else {
        prep_kernel<<<64, 256, 0, stream>>>(xyz, features, packed, featT);  // pack only
        ballq_kernel<<<(BB * SS) / 4, 256, 0, stream>>>(packed, new_xyz, idx);
        group_kernel<<<BB * 67 * (SS / 32), 256, 0, stream>>>(packed, new_xyz,
                                                              features, idx, out);
    }
}